// Round 1
// baseline (585.645 us; speedup 1.0000x reference)
//
#include <hip/hip_runtime.h>

#define F 128
#define NO 256            // NUM_IRREPS = 2*F
#define CHUNK 16
#define THREADS 256

// ws int layout:
//   [0..63]     counts
//   [64..127]   offsets
//   [128..191]  cursors
//   [192]       numChunks
//   [512..]     chunk descriptors, 3 ints each (species, start, cnt)
//   [16384..]   order (N ints, species-sorted node ids)
#define WS_COUNTS   0
#define WS_OFFSETS  64
#define WS_CURSORS  128
#define WS_NCHUNKS  192
#define WS_DESC     512
#define WS_ORDER    16384

__global__ void k_zero(int* wsI) {
    int t = blockIdx.x * blockDim.x + threadIdx.x;
    if (t < 64) wsI[WS_COUNTS + t] = 0;
}

__global__ void k_hist(const int* __restrict__ spec, int N, int* __restrict__ counts) {
    for (int i = blockIdx.x * blockDim.x + threadIdx.x; i < N; i += gridDim.x * blockDim.x)
        atomicAdd(&counts[spec[i]], 1);
}

__global__ void k_plan(int* wsI, int S) {
    __shared__ int sCounts[64], sOff[64], sCOff[64];
    int t = threadIdx.x;
    if (t < S) sCounts[t] = wsI[WS_COUNTS + t];
    __syncthreads();
    if (t == 0) {
        int acc = 0, cacc = 0;
        for (int s = 0; s < S; ++s) {
            sOff[s] = acc;  acc += sCounts[s];
            sCOff[s] = cacc; cacc += (sCounts[s] + CHUNK - 1) / CHUNK;
        }
        wsI[WS_NCHUNKS] = cacc;
    }
    __syncthreads();
    if (t < S) {
        wsI[WS_OFFSETS + t] = sOff[t];
        wsI[WS_CURSORS + t] = sOff[t];
        int cnt = sCounts[t], off = sOff[t], cb = sCOff[t];
        int nch = (cnt + CHUNK - 1) / CHUNK;
        for (int c = 0; c < nch; ++c) {
            int* d = &wsI[WS_DESC + 3 * (cb + c)];
            d[0] = t;
            d[1] = off + c * CHUNK;
            d[2] = min(CHUNK, cnt - c * CHUNK);
        }
    }
}

__global__ void k_scatter(const int* __restrict__ spec, int N,
                          int* __restrict__ cursors, int* __restrict__ order) {
    for (int i = blockIdx.x * blockDim.x + threadIdx.x; i < N; i += gridDim.x * blockDim.x) {
        int pos = atomicAdd(&cursors[spec[i]], 1);
        order[pos] = i;
    }
}

// LDS pool (floats):
//   s_out0 : [0, 2048)       [n][f]        (gated in place in phase 3)
//   s_x1   : [2048, 8192)    [n][d][f]     (becomes out1g in place)
//   s_c1   : [8192, 10240)   [n][f]
//   s_gate : [10240, 14336)  [n][o]
__global__ __launch_bounds__(THREADS) void k_main(
    const float* __restrict__ nf,
    const float* __restrict__ w0,
    const float* __restrict__ w1,
    const float* __restrict__ gk,
    const float* __restrict__ gb,
    const float* __restrict__ lw0,
    const float* __restrict__ lw1,
    const int* __restrict__ wsI,
    float* __restrict__ out)
{
    int b = blockIdx.x;
    if (b >= wsI[WS_NCHUNKS]) return;
    int s     = wsI[WS_DESC + 3 * b];
    int start = wsI[WS_DESC + 3 * b + 1];
    int cnt   = wsI[WS_DESC + 3 * b + 2];
    const int* order = &wsI[WS_ORDER];

    __shared__ float sp[14336];
    __shared__ int s_nid[CHUNK];

    int t = threadIdx.x;
    if (t < CHUNK) s_nid[t] = (t < cnt) ? order[start + t] : -1;
    __syncthreads();

    // ---- phase 1: paths ----
    #pragma unroll
    for (int it = 0; it < (CHUNK * F) / THREADS; ++it) {
        int idx = t + it * THREADS;
        int n = idx >> 7, f = idx & 127;
        int nid = s_nid[n];
        float x0 = 0.f, a = 0.f, bb = 0.f, c = 0.f;
        if (nid >= 0) {
            const float* p = nf + (size_t)nid * 512;
            x0 = p[f];
            a  = p[128 + f * 3 + 0];
            bb = p[128 + f * 3 + 1];
            c  = p[128 + f * 3 + 2];
        }
        float dot = a * a + bb * bb + c * c;
        const float* W0 = w0 + s * 5 * F + f;
        const float* W1 = w1 + s * 4 * F + f;
        float x0sq = x0 * x0;
        float o0 = x0 * W0[0] + x0sq * W0[F] + dot * W0[2 * F]
                 + x0sq * x0 * W0[3 * F] + x0 * dot * W0[4 * F];
        float c1 = W1[0] + x0 * W1[F] + x0sq * W1[2 * F] + dot * W1[3 * F];
        sp[n * F + f] = o0;
        sp[8192 + n * F + f] = c1;
        sp[2048 + n * 384 + 0 * F + f] = a;
        sp[2048 + n * 384 + 1 * F + f] = bb;
        sp[2048 + n * 384 + 2 * F + f] = c;
    }
    __syncthreads();

    // ---- phase 2: gate = out0 @ gk[s] + gb[s] ----
    {
        int o = t;
        const float* G = gk + (size_t)s * F * NO + o;
        float gbv = gb[s * NO + o];
        float acc[CHUNK];
        #pragma unroll
        for (int n = 0; n < CHUNK; ++n) acc[n] = gbv;
        for (int f0 = 0; f0 < F; f0 += 4) {
            float g0 = G[(f0 + 0) * NO];
            float g1 = G[(f0 + 1) * NO];
            float g2 = G[(f0 + 2) * NO];
            float g3 = G[(f0 + 3) * NO];
            #pragma unroll
            for (int n = 0; n < CHUNK; ++n) {
                float4 v = *(const float4*)&sp[n * F + f0];
                acc[n] += v.x * g0 + v.y * g1 + v.z * g2 + v.w * g3;
            }
        }
        #pragma unroll
        for (int n = 0; n < CHUNK; ++n) sp[10240 + n * NO + o] = acc[n];
    }
    __syncthreads();

    // ---- phase 3: apply gate in place ----
    #pragma unroll
    for (int it = 0; it < (CHUNK * F) / THREADS; ++it) {
        int idx = t + it * THREADS;
        int n = idx >> 7, f = idx & 127;
        float gate0 = sp[10240 + n * NO + f];
        float gate1 = sp[10240 + n * NO + F + f];
        sp[n * F + f] *= gate0;
        float c1g = sp[8192 + n * F + f] * gate1;
        sp[2048 + n * 384 + 0 * F + f] *= c1g;
        sp[2048 + n * 384 + 1 * F + f] *= c1g;
        sp[2048 + n * 384 + 2 * F + f] *= c1g;
    }
    __syncthreads();

    // ---- phase 4: linear layers ----
    {
        int oA = t, oB = t + 256;            // output columns in [0,512)
        bool isY0 = (oA < F);
        int colA, dA;
        if (isY0) { colA = oA; dA = 0; }
        else      { colA = (oA - F) / 3; dA = (oA - F) - 3 * colA; }
        int colB = (oB - F) / 3, dB = (oB - F) - 3 * colB;
        const float* WA = isY0 ? (lw0 + colA) : (lw1 + colA);
        const float* WB = lw1 + colB;
        int baseA   = isY0 ? 0 : (2048 + dA * F);
        int strideA = isY0 ? F : 384;
        int baseB   = 2048 + dB * F;

        float accA[CHUNK], accB[CHUNK];
        #pragma unroll
        for (int n = 0; n < CHUNK; ++n) { accA[n] = 0.f; accB[n] = 0.f; }
        for (int f0 = 0; f0 < F; f0 += 4) {
            float wa0 = WA[(f0 + 0) * F], wa1 = WA[(f0 + 1) * F];
            float wa2 = WA[(f0 + 2) * F], wa3 = WA[(f0 + 3) * F];
            float wb0 = WB[(f0 + 0) * F], wb1 = WB[(f0 + 1) * F];
            float wb2 = WB[(f0 + 2) * F], wb3 = WB[(f0 + 3) * F];
            #pragma unroll
            for (int n = 0; n < CHUNK; ++n) {
                float4 va = *(const float4*)&sp[baseA + n * strideA + f0];
                float4 vb = *(const float4*)&sp[baseB + n * 384 + f0];
                accA[n] += va.x * wa0 + va.y * wa1 + va.z * wa2 + va.w * wa3;
                accB[n] += vb.x * wb0 + vb.y * wb1 + vb.z * wb2 + vb.w * wb3;
            }
        }
        const float inv = 0.08838834764831845f; // 1/sqrt(128)
        #pragma unroll
        for (int n = 0; n < CHUNK; ++n) {
            int nid = s_nid[n];
            if (nid >= 0) {
                out[(size_t)nid * 512 + oA] = accA[n] * inv;
                out[(size_t)nid * 512 + oB] = accB[n] * inv;
            }
        }
    }
}

extern "C" void kernel_launch(void* const* d_in, const int* in_sizes, int n_in,
                              void* d_out, int out_size, void* d_ws, size_t ws_size,
                              hipStream_t stream) {
    const float* nf  = (const float*)d_in[0];
    const int*  spec = (const int*)d_in[1];
    const float* w0  = (const float*)d_in[2];
    const float* w1  = (const float*)d_in[3];
    const float* gk  = (const float*)d_in[4];
    const float* gb  = (const float*)d_in[5];
    const float* lw0 = (const float*)d_in[6];
    const float* lw1 = (const float*)d_in[7];
    float* out = (float*)d_out;

    int N = in_sizes[0] / (4 * F);
    int S = in_sizes[5] / NO;
    int* wsI = (int*)d_ws;

    k_zero<<<1, 256, 0, stream>>>(wsI);
    k_hist<<<256, 256, 0, stream>>>(spec, N, wsI + WS_COUNTS);
    k_plan<<<1, 64, 0, stream>>>(wsI, S);
    k_scatter<<<256, 256, 0, stream>>>(spec, N, wsI + WS_CURSORS, wsI + WS_ORDER);

    int maxc = (N + CHUNK - 1) / CHUNK + S;
    k_main<<<maxc, THREADS, 0, stream>>>(nf, w0, w1, gk, gb, lw0, lw1, wsI, out);
}

// Round 2
// 229.013 us; speedup vs baseline: 2.5573x; 2.5573x over previous
//
#include <hip/hip_runtime.h>

#define F 128
#define NO 256            // NUM_IRREPS = 2*F
#define CHUNK 16
#define THREADS 256

typedef short bf16x8 __attribute__((ext_vector_type(8)));
typedef float f32x4 __attribute__((ext_vector_type(4)));

// ws int layout
#define WS_COUNTS   0
#define WS_OFFSETS  64
#define WS_CURSORS  128
#define WS_NCHUNKS  192
#define WS_DESC     256      // 3 ints per chunk, up to ~3189 chunks
#define WS_ORDER    16384    // N ints
// ws byte offsets (weight panels)
#define WS_GKT_BYTES  (1u<<20)            // [S][256][128] bf16 = 4MB
#define WS_LW0T_BYTES (5u<<20)            // [128][128] bf16
#define WS_LW1T_BYTES ((5u<<20) + 32768)

__device__ __forceinline__ unsigned short f2bf(float x) {
    union { float f; unsigned u; } v; v.f = x;
    unsigned r = (v.u + 0x7FFFu + ((v.u >> 16) & 1u)) >> 16;
    return (unsigned short)r;
}
__device__ __forceinline__ unsigned pack2(float a, float b) {
    return (unsigned)f2bf(a) | ((unsigned)f2bf(b) << 16);
}

__global__ void k_zero(int* wsI) {
    int t = threadIdx.x;
    if (t < 64) wsI[WS_COUNTS + t] = 0;
}

__global__ void k_hist(const int* __restrict__ spec, int N, int* __restrict__ counts) {
    __shared__ int h[64];
    int t = threadIdx.x;
    if (t < 64) h[t] = 0;
    __syncthreads();
    for (int i = blockIdx.x * blockDim.x + t; i < N; i += gridDim.x * blockDim.x)
        atomicAdd(&h[spec[i]], 1);
    __syncthreads();
    if (t < 64) { int v = h[t]; if (v) atomicAdd(&counts[t], v); }
}

// 1 block, 64 threads (one wave): prefix sums + descriptor emit
__global__ void k_plan(int* wsI, int S) {
    int t = threadIdx.x;
    int cnt = (t < S) ? wsI[WS_COUNTS + t] : 0;
    int nch = (cnt + CHUNK - 1) / CHUNK;
    int x = cnt, y = nch;
    #pragma unroll
    for (int d = 1; d < 64; d <<= 1) {
        int vx = __shfl_up(x, d);
        int vy = __shfl_up(y, d);
        if (t >= d) { x += vx; y += vy; }
    }
    int off = x - cnt;
    int cbase = y - nch;
    if (t < S) {
        wsI[WS_OFFSETS + t] = off;
        wsI[WS_CURSORS + t] = off;
        for (int c = 0; c < nch; ++c) {
            int* dsc = &wsI[WS_DESC + 3 * (cbase + c)];
            dsc[0] = t;
            dsc[1] = off + c * CHUNK;
            dsc[2] = min(CHUNK, cnt - c * CHUNK);
        }
    }
    if (t == 63) wsI[WS_NCHUNKS] = y;
}

__global__ void k_scatter(const int* __restrict__ spec, int N,
                          int* __restrict__ cursors, int* __restrict__ order) {
    for (int i = blockIdx.x * blockDim.x + threadIdx.x; i < N; i += gridDim.x * blockDim.x) {
        int pos = atomicAdd(&cursors[spec[i]], 1);
        order[pos] = i;
    }
}

// transpose+convert gate_kernel: gk[s][k][o] fp32 -> gkT[s][o][k] bf16
__global__ __launch_bounds__(256) void k_prep_gk(const float* __restrict__ gk,
                                                 unsigned* __restrict__ gkT) {
    int s = blockIdx.x >> 1, kh = blockIdx.x & 1;
    __shared__ float tile[64][256];
    int t = threadIdx.x;
    const float* src = gk + ((size_t)s * F + kh * 64) * NO;
    #pragma unroll
    for (int it = 0; it < 16; ++it) {
        int idx4 = t + it * 256;
        int row = idx4 >> 6, col = (idx4 & 63) * 4;
        *(float4*)&tile[row][col] = *(const float4*)&src[row * NO + col];
    }
    __syncthreads();
    unsigned* dst = gkT + ((size_t)s * NO + t) * (F / 2) + kh * 32;
    #pragma unroll
    for (int k2 = 0; k2 < 32; ++k2)
        dst[k2] = pack2(tile[2 * k2][t], tile[2 * k2 + 1][t]);
}

// transpose+convert lin weights with 1/sqrt(F) folded: lw[k][g] -> lwT[g][k] bf16
__global__ __launch_bounds__(256) void k_prep_lw(const float* __restrict__ lw0,
                                                 const float* __restrict__ lw1,
                                                 unsigned* __restrict__ lw0T,
                                                 unsigned* __restrict__ lw1T) {
    const float* src = blockIdx.x ? lw1 : lw0;
    unsigned* dst = blockIdx.x ? lw1T : lw0T;
    __shared__ float tile[128][128];
    int t = threadIdx.x;
    #pragma unroll
    for (int it = 0; it < 16; ++it) {
        int idx4 = t + it * 256;
        int row = idx4 >> 5, col = (idx4 & 31) * 4;
        *(float4*)&tile[row][col] = *(const float4*)&src[row * F + col];
    }
    __syncthreads();
    const float inv = 0.08838834764831845f; // 1/sqrt(128)
    int g = t & 127, kh = t >> 7;
    unsigned* d = dst + g * (F / 2) + kh * 32;
    #pragma unroll
    for (int k2 = 0; k2 < 32; ++k2) {
        int k = kh * 64 + 2 * k2;
        d[k2] = pack2(tile[k][g] * inv, tile[k + 1][g] * inv);
    }
}

// main: one 16-node same-species chunk per block
__global__ __launch_bounds__(THREADS, 4) void k_main(
    const float* __restrict__ nf,
    const float* __restrict__ w0,
    const float* __restrict__ w1,
    const unsigned short* __restrict__ gkT,
    const float* __restrict__ gb,
    const unsigned short* __restrict__ lw0T,
    const unsigned short* __restrict__ lw1T,
    const int* __restrict__ wsI,
    float* __restrict__ out)
{
    int b = blockIdx.x;
    if (b >= wsI[WS_NCHUNKS]) return;
    int s     = wsI[WS_DESC + 3 * b];
    int start = wsI[WS_DESC + 3 * b + 1];
    int cnt   = wsI[WS_DESC + 3 * b + 2];

    __shared__ __align__(16) unsigned short s_ab[CHUNK * 136];       // out0 bf16, then out0g
    __shared__ __align__(16) unsigned short s_o1[3 * CHUNK * 136];   // out1g bf16 [d][n][k]
    __shared__ __align__(16) float s_gate[NO * 18];                  // gate fp32 [o][node(+pad)]
    __shared__ int s_nid[CHUNK];

    int t = threadIdx.x;
    if (t < CHUNK) s_nid[t] = (t < cnt) ? wsI[WS_ORDER + start + t] : -1;
    __syncthreads();

    int n = t >> 4, j = t & 15;     // node-in-chunk, f-group (f = 8j..8j+7)
    int nid = s_nid[n];

    // ---- phase 1: polynomial paths (all in registers) ----
    float xq[8], q[24];
    if (nid >= 0) {
        const float* p = nf + (size_t)nid * 512;
        *(float4*)&xq[0] = *(const float4*)&p[8 * j];
        *(float4*)&xq[4] = *(const float4*)&p[8 * j + 4];
        #pragma unroll
        for (int v = 0; v < 6; ++v)
            *(float4*)&q[4 * v] = *(const float4*)&p[128 + 24 * j + 4 * v];
    } else {
        #pragma unroll
        for (int i = 0; i < 8; ++i) xq[i] = 0.f;
        #pragma unroll
        for (int i = 0; i < 24; ++i) q[i] = 0.f;
    }
    float o0[8], c1[8];
    {
        const float* W0 = w0 + s * 5 * F + 8 * j;
        const float* W1 = w1 + s * 4 * F + 8 * j;
        float ph[5][8];
        #pragma unroll
        for (int i = 0; i < 8; ++i) {
            float a = q[3 * i], bb = q[3 * i + 1], c = q[3 * i + 2];
            float d0 = a * a + bb * bb + c * c;
            float x0 = xq[i], x2 = x0 * x0;
            ph[0][i] = x0; ph[1][i] = x2; ph[2][i] = d0;
            ph[3][i] = x2 * x0; ph[4][i] = x0 * d0;
        }
        #pragma unroll
        for (int i = 0; i < 8; ++i) o0[i] = 0.f;
        #pragma unroll
        for (int p = 0; p < 5; ++p) {
            float wr[8];
            *(float4*)&wr[0] = *(const float4*)&W0[p * F];
            *(float4*)&wr[4] = *(const float4*)&W0[p * F + 4];
            #pragma unroll
            for (int i = 0; i < 8; ++i) o0[i] += ph[p][i] * wr[i];
        }
        {
            float wr[8];
            *(float4*)&wr[0] = *(const float4*)&W1[0];
            *(float4*)&wr[4] = *(const float4*)&W1[4];
            #pragma unroll
            for (int i = 0; i < 8; ++i) c1[i] = wr[i];
        }
        #pragma unroll
        for (int p = 1; p < 4; ++p) {
            float wr[8];
            *(float4*)&wr[0] = *(const float4*)&W1[p * F];
            *(float4*)&wr[4] = *(const float4*)&W1[p * F + 4];
            #pragma unroll
            for (int i = 0; i < 8; ++i) c1[i] += ph[p - 1][i] * wr[i];
        }
    }
    {
        uint4 pk;
        pk.x = pack2(o0[0], o0[1]); pk.y = pack2(o0[2], o0[3]);
        pk.z = pack2(o0[4], o0[5]); pk.w = pack2(o0[6], o0[7]);
        *(uint4*)&s_ab[n * 136 + 8 * j] = pk;
    }
    __syncthreads();

    // ---- phase 2: gate = out0 @ gk + gb via MFMA (D[o][node]) ----
    int lane = t & 63, w = t >> 6;
    int lr = lane & 15, lg = lane >> 4;
    {
        bf16x8 bfr[4];
        #pragma unroll
        for (int kk = 0; kk < 4; ++kk)
            bfr[kk] = *(const bf16x8*)&s_ab[lr * 136 + kk * 32 + lg * 8];
        #pragma unroll
        for (int q4 = 0; q4 < 4; ++q4) {
            int orow = (w + 4 * q4) * 16;
            float4 gbv = *(const float4*)&gb[s * NO + orow + lg * 4];
            f32x4 acc; acc[0] = gbv.x; acc[1] = gbv.y; acc[2] = gbv.z; acc[3] = gbv.w;
            const unsigned short* ga = gkT + ((size_t)(s * NO + orow + lr)) * F + lg * 8;
            #pragma unroll
            for (int kk = 0; kk < 4; ++kk) {
                bf16x8 af = *(const bf16x8*)(ga + kk * 32);
                acc = __builtin_amdgcn_mfma_f32_16x16x32_bf16(af, bfr[kk], acc, 0, 0, 0);
            }
            #pragma unroll
            for (int r = 0; r < 4; ++r)
                s_gate[(orow + lg * 4 + r) * 18 + lr] = acc[r];
        }
    }
    __syncthreads();

    // ---- phase 3: apply gate, emit bf16 out0g / out1g ----
    {
        #pragma unroll
        for (int i = 0; i < 8; ++i) {
            o0[i] *= s_gate[(8 * j + i) * 18 + n];
            c1[i] *= s_gate[(F + 8 * j + i) * 18 + n];
        }
        uint4 pk;
        pk.x = pack2(o0[0], o0[1]); pk.y = pack2(o0[2], o0[3]);
        pk.z = pack2(o0[4], o0[5]); pk.w = pack2(o0[6], o0[7]);
        *(uint4*)&s_ab[n * 136 + 8 * j] = pk;
        #pragma unroll
        for (int d = 0; d < 3; ++d) {
            uint4 p1;
            p1.x = pack2(c1[0] * q[d],      c1[1] * q[3 + d]);
            p1.y = pack2(c1[2] * q[6 + d],  c1[3] * q[9 + d]);
            p1.z = pack2(c1[4] * q[12 + d], c1[5] * q[15 + d]);
            p1.w = pack2(c1[6] * q[18 + d], c1[7] * q[21 + d]);
            *(uint4*)&s_o1[(d * CHUNK + n) * 136 + 8 * j] = p1;
        }
    }
    __syncthreads();

    // ---- phase 4: y0 = out0g@lw0T^T, y1 = out1g@lw1T^T via MFMA ----
    int nid2 = s_nid[lr];
    #pragma unroll
    for (int gi = 0; gi < 2; ++gi) {
        int gr = (2 * w + gi) * 16;
        {
            f32x4 acc = {0.f, 0.f, 0.f, 0.f};
            const unsigned short* la = lw0T + (gr + lr) * F + lg * 8;
            #pragma unroll
            for (int kk = 0; kk < 4; ++kk) {
                bf16x8 af = *(const bf16x8*)(la + kk * 32);
                bf16x8 bf = *(const bf16x8*)&s_ab[lr * 136 + kk * 32 + lg * 8];
                acc = __builtin_amdgcn_mfma_f32_16x16x32_bf16(af, bf, acc, 0, 0, 0);
            }
            if (nid2 >= 0) {
                float4 st; st.x = acc[0]; st.y = acc[1]; st.z = acc[2]; st.w = acc[3];
                *(float4*)&out[(size_t)nid2 * 512 + gr + lg * 4] = st;
            }
        }
        const unsigned short* la1 = lw1T + (gr + lr) * F + lg * 8;
        bf16x8 af1[4];
        #pragma unroll
        for (int kk = 0; kk < 4; ++kk) af1[kk] = *(const bf16x8*)(la1 + kk * 32);
        #pragma unroll
        for (int d = 0; d < 3; ++d) {
            f32x4 acc = {0.f, 0.f, 0.f, 0.f};
            #pragma unroll
            for (int kk = 0; kk < 4; ++kk) {
                bf16x8 bf = *(const bf16x8*)&s_o1[(d * CHUNK + lr) * 136 + kk * 32 + lg * 8];
                acc = __builtin_amdgcn_mfma_f32_16x16x32_bf16(af1[kk], bf, acc, 0, 0, 0);
            }
            if (nid2 >= 0) {
                #pragma unroll
                for (int r = 0; r < 4; ++r)
                    out[(size_t)nid2 * 512 + F + (gr + lg * 4 + r) * 3 + d] = acc[r];
            }
        }
    }
}

extern "C" void kernel_launch(void* const* d_in, const int* in_sizes, int n_in,
                              void* d_out, int out_size, void* d_ws, size_t ws_size,
                              hipStream_t stream) {
    const float* nf  = (const float*)d_in[0];
    const int*  spec = (const int*)d_in[1];
    const float* w0  = (const float*)d_in[2];
    const float* w1  = (const float*)d_in[3];
    const float* gk  = (const float*)d_in[4];
    const float* gb  = (const float*)d_in[5];
    const float* lw0 = (const float*)d_in[6];
    const float* lw1 = (const float*)d_in[7];
    float* out = (float*)d_out;

    int N = in_sizes[0] / (4 * F);
    int S = in_sizes[5] / NO;
    int* wsI = (int*)d_ws;
    unsigned* gkT  = (unsigned*)((char*)d_ws + WS_GKT_BYTES);
    unsigned* lw0T = (unsigned*)((char*)d_ws + WS_LW0T_BYTES);
    unsigned* lw1T = (unsigned*)((char*)d_ws + WS_LW1T_BYTES);

    k_zero<<<1, 64, 0, stream>>>(wsI);
    k_hist<<<64, 256, 0, stream>>>(spec, N, wsI + WS_COUNTS);
    k_plan<<<1, 64, 0, stream>>>(wsI, S);
    k_scatter<<<256, 256, 0, stream>>>(spec, N, wsI + WS_CURSORS, wsI + WS_ORDER);
    k_prep_gk<<<2 * S, 256, 0, stream>>>(gk, gkT);
    k_prep_lw<<<2, 256, 0, stream>>>(lw0, lw1, lw0T, lw1T);

    int maxc = (N + CHUNK - 1) / CHUNK + S;
    k_main<<<maxc, THREADS, 0, stream>>>(nf, w0, w1,
                                         (const unsigned short*)gkT, gb,
                                         (const unsigned short*)lw0T,
                                         (const unsigned short*)lw1T,
                                         wsI, out);
}

// Round 3
// 143.869 us; speedup vs baseline: 4.0707x; 1.5918x over previous
//
#include <hip/hip_runtime.h>

#define F 128
#define NO 256            // NUM_IRREPS = 2*F
#define CHUNK 32
#define THREADS 256
#define NBLK_HIST 64

typedef short bf16x8 __attribute__((ext_vector_type(8)));
typedef float f32x4 __attribute__((ext_vector_type(4)));

// ws int layout
#define WS_COUNTS   0      // 64 ints
#define WS_OFFSETS  64
#define WS_NCHUNKS  192
#define WS_DESC     256    // 3 ints per chunk (<5200 used)
#define WS_BC       8192   // [64 hist-blocks][64 species]
#define WS_ORDER    16384  // N ints
// ws byte offsets (weight panels)
#define WS_GKFRAG  (1u<<20)             // [S*16 ot][4 kk][64 lane][8] bf16 = 4MB
#define WS_LW0FRAG (5u<<20)             // [8 gt][4 kk][64][8] bf16 = 32KB
#define WS_LW1FRAG ((5u<<20) + 32768)

__device__ __forceinline__ unsigned short f2bf(float x) {
    union { float f; unsigned u; } v; v.f = x;
    unsigned r = (v.u + 0x7FFFu + ((v.u >> 16) & 1u)) >> 16;
    return (unsigned short)r;
}
__device__ __forceinline__ unsigned pack2(float a, float b) {
    return (unsigned)f2bf(a) | ((unsigned)f2bf(b) << 16);
}

// ---- prep: weight fragments (and zero counts) ----
__global__ __launch_bounds__(256) void k_prep(const float* __restrict__ gk,
                                              const float* __restrict__ lw0,
                                              const float* __restrict__ lw1,
                                              int* __restrict__ wsI,
                                              unsigned* __restrict__ gkfrag,
                                              unsigned* __restrict__ lw0f,
                                              unsigned* __restrict__ lw1f,
                                              int S) {
    int t = threadIdx.x, lane = t & 63, grp = t >> 6;
    int lr = lane & 15, lg = lane >> 4;
    int b = blockIdx.x;
    if (b < S) {
        const float* src = gk + (size_t)b * F * NO;
        #pragma unroll
        for (int it = 0; it < 4; ++it) {
            int ot = grp * 4 + it;
            #pragma unroll
            for (int kk = 0; kk < 4; ++kk) {
                float v[8];
                #pragma unroll
                for (int e = 0; e < 8; ++e)
                    v[e] = src[(kk * 32 + lg * 8 + e) * NO + ot * 16 + lr];
                uint4 pk;
                pk.x = pack2(v[0], v[1]); pk.y = pack2(v[2], v[3]);
                pk.z = pack2(v[4], v[5]); pk.w = pack2(v[6], v[7]);
                *(uint4*)((char*)gkfrag + ((size_t)((b * 16 + ot) * 4 + kk) * 1024) + lane * 16) = pk;
            }
        }
    } else if (b == S || b == S + 1) {
        const float* src = (b == S) ? lw0 : lw1;
        unsigned* dst = (b == S) ? lw0f : lw1f;
        const float inv = 0.08838834764831845f; // 1/sqrt(128)
        #pragma unroll
        for (int it = 0; it < 2; ++it) {
            int gt = grp * 2 + it;
            #pragma unroll
            for (int kk = 0; kk < 4; ++kk) {
                float v[8];
                #pragma unroll
                for (int e = 0; e < 8; ++e)
                    v[e] = src[(kk * 32 + lg * 8 + e) * F + gt * 16 + lr] * inv;
                uint4 pk;
                pk.x = pack2(v[0], v[1]); pk.y = pack2(v[2], v[3]);
                pk.z = pack2(v[4], v[5]); pk.w = pack2(v[6], v[7]);
                *(uint4*)((char*)dst + ((gt * 4 + kk) * 1024) + lane * 16) = pk;
            }
        }
        if (b == S && t < 64) wsI[WS_COUNTS + t] = 0;
    }
}

// ---- hist: per-block counts + global counts ----
__global__ void k_hist(const int* __restrict__ spec, int N, int* __restrict__ wsI) {
    __shared__ int h[64];
    int t = threadIdx.x, b = blockIdx.x;
    if (t < 64) h[t] = 0;
    __syncthreads();
    int per = (N + NBLK_HIST - 1) / NBLK_HIST;
    int lo = b * per, hi = min(N, lo + per);
    for (int i = lo + t; i < hi; i += 256) atomicAdd(&h[spec[i]], 1);
    __syncthreads();
    if (t < 64) {
        wsI[WS_BC + b * 64 + t] = h[t];
        if (h[t]) atomicAdd(&wsI[WS_COUNTS + t], h[t]);
    }
}

// ---- plan: prefix sums, per-block bases, chunk descriptors ----
__global__ void k_plan(int* __restrict__ wsI, int S) {
    int t = threadIdx.x;
    int cnt = (t < S) ? wsI[WS_COUNTS + t] : 0;
    int nch = (cnt + CHUNK - 1) / CHUNK;
    int x = cnt, y = nch;
    #pragma unroll
    for (int d = 1; d < 64; d <<= 1) {
        int vx = __shfl_up(x, d);
        int vy = __shfl_up(y, d);
        if (t >= d) { x += vx; y += vy; }
    }
    int off = x - cnt, cbase = y - nch;
    if (t < S) {
        wsI[WS_OFFSETS + t] = off;
        int run = off;
        for (int b2 = 0; b2 < NBLK_HIST; ++b2) {
            int tmp = wsI[WS_BC + b2 * 64 + t];
            wsI[WS_BC + b2 * 64 + t] = run;
            run += tmp;
        }
        for (int c = 0; c < nch; ++c) {
            int* dsc = &wsI[WS_DESC + 3 * (cbase + c)];
            dsc[0] = t;
            dsc[1] = off + c * CHUNK;
            dsc[2] = min(CHUNK, cnt - c * CHUNK);
        }
    }
    if (t == 63) wsI[WS_NCHUNKS] = y;
}

// ---- scatter: blockwise deterministic-output scatter ----
__global__ void k_scatter(const int* __restrict__ spec, int N, int* __restrict__ wsI) {
    __shared__ int cur[64];
    int t = threadIdx.x, b = blockIdx.x;
    if (t < 64) cur[t] = wsI[WS_BC + b * 64 + t];
    __syncthreads();
    int per = (N + NBLK_HIST - 1) / NBLK_HIST;
    int lo = b * per, hi = min(N, lo + per);
    for (int i = lo + t; i < hi; i += 256) {
        int pos = atomicAdd(&cur[spec[i]], 1);
        wsI[WS_ORDER + pos] = i;
    }
}

// ---- main: one 32-node same-species chunk per block ----
__global__ __launch_bounds__(THREADS, 3) void k_main(
    const float* __restrict__ nf,
    const float* __restrict__ w0,
    const float* __restrict__ w1,
    const unsigned short* __restrict__ gkfrag,
    const float* __restrict__ gb,
    const unsigned short* __restrict__ lw0f,
    const unsigned short* __restrict__ lw1f,
    const int* __restrict__ wsI,
    float* __restrict__ out)
{
    int b = blockIdx.x;
    if (b >= wsI[WS_NCHUNKS]) return;
    int s     = wsI[WS_DESC + 3 * b];
    int start = wsI[WS_DESC + 3 * b + 1];
    int cnt   = wsI[WS_DESC + 3 * b + 2];

    __shared__ __align__(16) unsigned short s_ab[CHUNK * 136];   // out0 bf16 -> out0g bf16
    __shared__ __align__(16) float s_u[CHUNK * 268];             // union: gate f32 / out1g bf16 [3][32][136]
    __shared__ int s_nid[CHUNK];

    int t = threadIdx.x;
    int lane = t & 63, w = t >> 6, lr = lane & 15, lg = lane >> 4;
    int n = t >> 3, j = t & 7, f0 = j * 16;

    int nid = (n < cnt) ? wsI[WS_ORDER + start + n] : -1;
    if (j == 0) s_nid[n] = nid;

    const float* p = nf + (size_t)(nid >= 0 ? nid : 0) * 512;

    // ---- phase 1: polynomial paths (registers) ----
    float x0[16], dot[16], o0[16], c1[16];
    {
        #pragma unroll
        for (int v = 0; v < 4; ++v)
            *(float4*)&x0[4 * v] = *(const float4*)&p[f0 + 4 * v];
        #pragma unroll
        for (int h = 0; h < 2; ++h) {
            float q[24];
            #pragma unroll
            for (int v = 0; v < 6; ++v)
                *(float4*)&q[4 * v] = *(const float4*)&p[128 + f0 * 3 + 24 * h + 4 * v];
            #pragma unroll
            for (int i = 0; i < 8; ++i)
                dot[8 * h + i] = q[3 * i] * q[3 * i] + q[3 * i + 1] * q[3 * i + 1] + q[3 * i + 2] * q[3 * i + 2];
        }
        if (nid < 0) {
            #pragma unroll
            for (int i = 0; i < 16; ++i) { x0[i] = 0.f; dot[i] = 0.f; }
        }
        const float* W0 = w0 + s * 5 * F + f0;
        const float* W1 = w1 + s * 4 * F + f0;
        float wr[16];
        #define LOADW(base) { \
            *(float4*)&wr[0]  = *(const float4*)&(base)[0]; \
            *(float4*)&wr[4]  = *(const float4*)&(base)[4]; \
            *(float4*)&wr[8]  = *(const float4*)&(base)[8]; \
            *(float4*)&wr[12] = *(const float4*)&(base)[12]; }
        LOADW(W0);
        #pragma unroll
        for (int i = 0; i < 16; ++i) o0[i] = x0[i] * wr[i];
        LOADW((W0 + F));
        #pragma unroll
        for (int i = 0; i < 16; ++i) o0[i] += x0[i] * x0[i] * wr[i];
        LOADW((W0 + 2 * F));
        #pragma unroll
        for (int i = 0; i < 16; ++i) o0[i] += dot[i] * wr[i];
        LOADW((W0 + 3 * F));
        #pragma unroll
        for (int i = 0; i < 16; ++i) o0[i] += x0[i] * x0[i] * x0[i] * wr[i];
        LOADW((W0 + 4 * F));
        #pragma unroll
        for (int i = 0; i < 16; ++i) o0[i] += x0[i] * dot[i] * wr[i];
        LOADW(W1);
        #pragma unroll
        for (int i = 0; i < 16; ++i) c1[i] = wr[i];
        LOADW((W1 + F));
        #pragma unroll
        for (int i = 0; i < 16; ++i) c1[i] += x0[i] * wr[i];
        LOADW((W1 + 2 * F));
        #pragma unroll
        for (int i = 0; i < 16; ++i) c1[i] += x0[i] * x0[i] * wr[i];
        LOADW((W1 + 3 * F));
        #pragma unroll
        for (int i = 0; i < 16; ++i) c1[i] += dot[i] * wr[i];
        #undef LOADW
    }
    {
        uint4 pk0, pk1;
        pk0.x = pack2(o0[0], o0[1]);  pk0.y = pack2(o0[2], o0[3]);
        pk0.z = pack2(o0[4], o0[5]);  pk0.w = pack2(o0[6], o0[7]);
        pk1.x = pack2(o0[8], o0[9]);  pk1.y = pack2(o0[10], o0[11]);
        pk1.z = pack2(o0[12], o0[13]); pk1.w = pack2(o0[14], o0[15]);
        *(uint4*)&s_ab[n * 136 + f0] = pk0;
        *(uint4*)&s_ab[n * 136 + f0 + 8] = pk1;
    }

    // prefetch gate-kernel B-fragments (per wave: ot = 4w..4w+3)
    bf16x8 Bg[4][4];
    {
        const unsigned short* gkb = gkfrag + (size_t)((s * 16 + 4 * w) * 4) * 512 + lane * 8;
        #pragma unroll
        for (int oi = 0; oi < 4; ++oi)
            #pragma unroll
            for (int kk = 0; kk < 4; ++kk)
                Bg[oi][kk] = *(const bf16x8*)(gkb + (oi * 4 + kk) * 512);
    }
    __syncthreads();   // B1: s_ab ready

    // ---- phase 2: gate = out0 @ gk + gb, D[node][o] ----
    {
        int obase = w * 64;
        float gbv[4];
        #pragma unroll
        for (int oi = 0; oi < 4; ++oi) gbv[oi] = gb[s * NO + obase + oi * 16 + lr];
        #pragma unroll
        for (int nt = 0; nt < 2; ++nt) {
            bf16x8 A[4];
            #pragma unroll
            for (int kk = 0; kk < 4; ++kk)
                A[kk] = *(const bf16x8*)&s_ab[(nt * 16 + lr) * 136 + kk * 32 + lg * 8];
            #pragma unroll
            for (int oi = 0; oi < 4; ++oi) {
                f32x4 acc; acc[0] = gbv[oi]; acc[1] = gbv[oi]; acc[2] = gbv[oi]; acc[3] = gbv[oi];
                #pragma unroll
                for (int kk = 0; kk < 4; ++kk)
                    acc = __builtin_amdgcn_mfma_f32_16x16x32_bf16(A[kk], Bg[oi][kk], acc, 0, 0, 0);
                #pragma unroll
                for (int r = 0; r < 4; ++r)
                    s_u[(nt * 16 + lg * 4 + r) * 268 + obase + oi * 16 + lr] = acc[r];
            }
        }
    }
    __syncthreads();   // B2: gate ready

    // ---- phase 3a: read gate to regs ----
    float g0[16], g1[16];
    #pragma unroll
    for (int v = 0; v < 4; ++v)
        *(float4*)&g0[4 * v] = *(const float4*)&s_u[n * 268 + f0 + 4 * v];
    #pragma unroll
    for (int v = 0; v < 4; ++v)
        *(float4*)&g1[4 * v] = *(const float4*)&s_u[n * 268 + 128 + f0 + 4 * v];
    __syncthreads();   // B3: gate region reusable

    // ---- phase 3b: apply gate; emit out0g -> s_ab, out1g -> s_o1 (union) ----
    unsigned short* s_o1 = (unsigned short*)s_u;
    {
        #pragma unroll
        for (int i = 0; i < 16; ++i) { o0[i] *= g0[i]; c1[i] *= g1[i]; }
        uint4 pk0, pk1;
        pk0.x = pack2(o0[0], o0[1]);  pk0.y = pack2(o0[2], o0[3]);
        pk0.z = pack2(o0[4], o0[5]);  pk0.w = pack2(o0[6], o0[7]);
        pk1.x = pack2(o0[8], o0[9]);  pk1.y = pack2(o0[10], o0[11]);
        pk1.z = pack2(o0[12], o0[13]); pk1.w = pack2(o0[14], o0[15]);
        *(uint4*)&s_ab[n * 136 + f0] = pk0;
        *(uint4*)&s_ab[n * 136 + f0 + 8] = pk1;
    }
    // prefetch lin-weight B-fragments (per wave: gt = 2w, 2w+1)
    bf16x8 L0[2][4], L1[2][4];
    {
        const unsigned short* l0b = lw0f + (size_t)(w * 2 * 4) * 512 + lane * 8;
        const unsigned short* l1b = lw1f + (size_t)(w * 2 * 4) * 512 + lane * 8;
        #pragma unroll
        for (int gi = 0; gi < 2; ++gi)
            #pragma unroll
            for (int kk = 0; kk < 4; ++kk) {
                L0[gi][kk] = *(const bf16x8*)(l0b + (gi * 4 + kk) * 512);
                L1[gi][kk] = *(const bf16x8*)(l1b + (gi * 4 + kk) * 512);
            }
    }
    {
        #pragma unroll
        for (int h = 0; h < 2; ++h) {
            float q[24];
            #pragma unroll
            for (int v = 0; v < 6; ++v)
                *(float4*)&q[4 * v] = *(const float4*)&p[128 + f0 * 3 + 24 * h + 4 * v];
            if (nid < 0) {
                #pragma unroll
                for (int i = 0; i < 24; ++i) q[i] = 0.f;
            }
            #pragma unroll
            for (int d = 0; d < 3; ++d) {
                uint4 pk;
                pk.x = pack2(c1[8 * h + 0] * q[0 + d],  c1[8 * h + 1] * q[3 + d]);
                pk.y = pack2(c1[8 * h + 2] * q[6 + d],  c1[8 * h + 3] * q[9 + d]);
                pk.z = pack2(c1[8 * h + 4] * q[12 + d], c1[8 * h + 5] * q[15 + d]);
                pk.w = pack2(c1[8 * h + 6] * q[18 + d], c1[8 * h + 7] * q[21 + d]);
                *(uint4*)&s_o1[(d * CHUNK + n) * 136 + f0 + 8 * h] = pk;
            }
        }
    }
    __syncthreads();   // B4: out0g/out1g ready

    // ---- phase 4: y0 / y1 via MFMA, D[node][g], coalesced stores ----
    {
        int gbase = w * 32;
        #pragma unroll
        for (int nt = 0; nt < 2; ++nt) {
            int nids[4];
            #pragma unroll
            for (int r = 0; r < 4; ++r) nids[r] = s_nid[nt * 16 + lg * 4 + r];
            bf16x8 A[4];
            #pragma unroll
            for (int kk = 0; kk < 4; ++kk)
                A[kk] = *(const bf16x8*)&s_ab[(nt * 16 + lr) * 136 + kk * 32 + lg * 8];
            #pragma unroll
            for (int gi = 0; gi < 2; ++gi) {
                f32x4 acc = {0.f, 0.f, 0.f, 0.f};
                #pragma unroll
                for (int kk = 0; kk < 4; ++kk)
                    acc = __builtin_amdgcn_mfma_f32_16x16x32_bf16(A[kk], L0[gi][kk], acc, 0, 0, 0);
                #pragma unroll
                for (int r = 0; r < 4; ++r)
                    if (nids[r] >= 0)
                        out[(size_t)nids[r] * 512 + gbase + gi * 16 + lr] = acc[r];
            }
            #pragma unroll
            for (int d = 0; d < 3; ++d) {
                bf16x8 Ad[4];
                #pragma unroll
                for (int kk = 0; kk < 4; ++kk)
                    Ad[kk] = *(const bf16x8*)&s_o1[(d * CHUNK + nt * 16 + lr) * 136 + kk * 32 + lg * 8];
                #pragma unroll
                for (int gi = 0; gi < 2; ++gi) {
                    f32x4 acc = {0.f, 0.f, 0.f, 0.f};
                    #pragma unroll
                    for (int kk = 0; kk < 4; ++kk)
                        acc = __builtin_amdgcn_mfma_f32_16x16x32_bf16(Ad[kk], L1[gi][kk], acc, 0, 0, 0);
                    #pragma unroll
                    for (int r = 0; r < 4; ++r)
                        if (nids[r] >= 0)
                            out[(size_t)nids[r] * 512 + F + (gbase + gi * 16 + lr) * 3 + d] = acc[r];
                }
            }
        }
    }
}

extern "C" void kernel_launch(void* const* d_in, const int* in_sizes, int n_in,
                              void* d_out, int out_size, void* d_ws, size_t ws_size,
                              hipStream_t stream) {
    const float* nf  = (const float*)d_in[0];
    const int*  spec = (const int*)d_in[1];
    const float* w0  = (const float*)d_in[2];
    const float* w1  = (const float*)d_in[3];
    const float* gk  = (const float*)d_in[4];
    const float* gb  = (const float*)d_in[5];
    const float* lw0 = (const float*)d_in[6];
    const float* lw1 = (const float*)d_in[7];
    float* out = (float*)d_out;

    int N = in_sizes[0] / (4 * F);
    int S = in_sizes[5] / NO;
    int* wsI = (int*)d_ws;
    unsigned* gkfrag = (unsigned*)((char*)d_ws + WS_GKFRAG);
    unsigned* lw0f   = (unsigned*)((char*)d_ws + WS_LW0FRAG);
    unsigned* lw1f   = (unsigned*)((char*)d_ws + WS_LW1FRAG);

    k_prep<<<S + 2, 256, 0, stream>>>(gk, lw0, lw1, wsI, gkfrag, lw0f, lw1f, S);
    k_hist<<<NBLK_HIST, 256, 0, stream>>>(spec, N, wsI);
    k_plan<<<1, 64, 0, stream>>>(wsI, S);
    k_scatter<<<NBLK_HIST, 256, 0, stream>>>(spec, N, wsI);

    int maxc = (N + CHUNK - 1) / CHUNK + S;
    k_main<<<maxc, THREADS, 0, stream>>>(nf, w0, w1,
                                         (const unsigned short*)gkfrag, gb,
                                         (const unsigned short*)lw0f,
                                         (const unsigned short*)lw1f,
                                         wsI, out);
}

// Round 4
// 135.728 us; speedup vs baseline: 4.3148x; 1.0600x over previous
//
#include <hip/hip_runtime.h>

#define F 128
#define NO 256            // NUM_IRREPS = 2*F
#define CHUNK 32
#define THREADS 256
#define NBLK_HIST 64

typedef short bf16x8 __attribute__((ext_vector_type(8)));
typedef float f32x4 __attribute__((ext_vector_type(4)));

// ws int layout
#define WS_COUNTS   0      // 64 ints
#define WS_OFFSETS  64
#define WS_NCHUNKS  192
#define WS_DESC     256    // 3 ints per chunk (<5200 used)
#define WS_BC       8192   // [64 hist-blocks][64 species]
#define WS_ORDER    16384  // N ints
// ws byte offsets (weight panels)
#define WS_GKFRAG  (1u<<20)             // [S*16 ot][4 kk][64 lane][8] bf16 = 4MB
#define WS_LW0FRAG (5u<<20)             // [8 gt][4 kk][64][8] bf16 = 32KB
#define WS_LW1FRAG ((5u<<20) + 32768)

__device__ __forceinline__ unsigned short f2bf(float x) {
    union { float f; unsigned u; } v; v.f = x;
    unsigned r = (v.u + 0x7FFFu + ((v.u >> 16) & 1u)) >> 16;
    return (unsigned short)r;
}
__device__ __forceinline__ unsigned pack2(float a, float b) {
    return (unsigned)f2bf(a) | ((unsigned)f2bf(b) << 16);
}

// ---- prep: weight fragments (and zero counts) ----
__global__ __launch_bounds__(256) void k_prep(const float* __restrict__ gk,
                                              const float* __restrict__ lw0,
                                              const float* __restrict__ lw1,
                                              int* __restrict__ wsI,
                                              unsigned* __restrict__ gkfrag,
                                              unsigned* __restrict__ lw0f,
                                              unsigned* __restrict__ lw1f,
                                              int S) {
    int t = threadIdx.x, lane = t & 63, grp = t >> 6;
    int lr = lane & 15, lg = lane >> 4;
    int b = blockIdx.x;
    if (b < S) {
        const float* src = gk + (size_t)b * F * NO;
        #pragma unroll
        for (int it = 0; it < 4; ++it) {
            int ot = grp * 4 + it;
            #pragma unroll
            for (int kk = 0; kk < 4; ++kk) {
                float v[8];
                #pragma unroll
                for (int e = 0; e < 8; ++e)
                    v[e] = src[(kk * 32 + lg * 8 + e) * NO + ot * 16 + lr];
                uint4 pk;
                pk.x = pack2(v[0], v[1]); pk.y = pack2(v[2], v[3]);
                pk.z = pack2(v[4], v[5]); pk.w = pack2(v[6], v[7]);
                *(uint4*)((char*)gkfrag + ((size_t)((b * 16 + ot) * 4 + kk) * 1024) + lane * 16) = pk;
            }
        }
    } else if (b == S || b == S + 1) {
        const float* src = (b == S) ? lw0 : lw1;
        unsigned* dst = (b == S) ? lw0f : lw1f;
        const float inv = 0.08838834764831845f; // 1/sqrt(128)
        #pragma unroll
        for (int it = 0; it < 2; ++it) {
            int gt = grp * 2 + it;
            #pragma unroll
            for (int kk = 0; kk < 4; ++kk) {
                float v[8];
                #pragma unroll
                for (int e = 0; e < 8; ++e)
                    v[e] = src[(kk * 32 + lg * 8 + e) * F + gt * 16 + lr] * inv;
                uint4 pk;
                pk.x = pack2(v[0], v[1]); pk.y = pack2(v[2], v[3]);
                pk.z = pack2(v[4], v[5]); pk.w = pack2(v[6], v[7]);
                *(uint4*)((char*)dst + ((gt * 4 + kk) * 1024) + lane * 16) = pk;
            }
        }
        if (b == S && t < 64) wsI[WS_COUNTS + t] = 0;
    }
}

// ---- hist: per-block counts + global counts ----
__global__ void k_hist(const int* __restrict__ spec, int N, int* __restrict__ wsI) {
    __shared__ int h[64];
    int t = threadIdx.x, b = blockIdx.x;
    if (t < 64) h[t] = 0;
    __syncthreads();
    int per = (N + NBLK_HIST - 1) / NBLK_HIST;
    int lo = b * per, hi = min(N, lo + per);
    for (int i = lo + t; i < hi; i += 256) atomicAdd(&h[spec[i]], 1);
    __syncthreads();
    if (t < 64) {
        wsI[WS_BC + b * 64 + t] = h[t];
        if (h[t]) atomicAdd(&wsI[WS_COUNTS + t], h[t]);
    }
}

// ---- plan: prefix sums, per-block bases, chunk descriptors ----
__global__ void k_plan(int* __restrict__ wsI, int S) {
    int t = threadIdx.x;
    int cnt = (t < S) ? wsI[WS_COUNTS + t] : 0;
    int nch = (cnt + CHUNK - 1) / CHUNK;
    int x = cnt, y = nch;
    #pragma unroll
    for (int d = 1; d < 64; d <<= 1) {
        int vx = __shfl_up(x, d);
        int vy = __shfl_up(y, d);
        if (t >= d) { x += vx; y += vy; }
    }
    int off = x - cnt, cbase = y - nch;
    if (t < S) {
        wsI[WS_OFFSETS + t] = off;
        int run = off;
        for (int b2 = 0; b2 < NBLK_HIST; ++b2) {
            int tmp = wsI[WS_BC + b2 * 64 + t];
            wsI[WS_BC + b2 * 64 + t] = run;
            run += tmp;
        }
        for (int c = 0; c < nch; ++c) {
            int* dsc = &wsI[WS_DESC + 3 * (cbase + c)];
            dsc[0] = t;
            dsc[1] = off + c * CHUNK;
            dsc[2] = min(CHUNK, cnt - c * CHUNK);
        }
    }
    if (t == 63) wsI[WS_NCHUNKS] = y;
}

// ---- scatter: blockwise deterministic-output scatter ----
__global__ void k_scatter(const int* __restrict__ spec, int N, int* __restrict__ wsI) {
    __shared__ int cur[64];
    int t = threadIdx.x, b = blockIdx.x;
    if (t < 64) cur[t] = wsI[WS_BC + b * 64 + t];
    __syncthreads();
    int per = (N + NBLK_HIST - 1) / NBLK_HIST;
    int lo = b * per, hi = min(N, lo + per);
    for (int i = lo + t; i < hi; i += 256) {
        int pos = atomicAdd(&cur[spec[i]], 1);
        wsI[WS_ORDER + pos] = i;
    }
}

// ---- main: one 32-node same-species chunk per block ----
__global__ __launch_bounds__(THREADS, 3) void k_main(
    const float* __restrict__ nf,
    const float* __restrict__ w0,
    const float* __restrict__ w1,
    const unsigned short* __restrict__ gkfrag,
    const float* __restrict__ gb,
    const unsigned short* __restrict__ lw0f,
    const unsigned short* __restrict__ lw1f,
    const int* __restrict__ wsI,
    float* __restrict__ out)
{
    int b = blockIdx.x;
    if (b >= wsI[WS_NCHUNKS]) return;
    int s     = wsI[WS_DESC + 3 * b];
    int start = wsI[WS_DESC + 3 * b + 1];
    int cnt   = wsI[WS_DESC + 3 * b + 2];

    __shared__ __align__(16) unsigned short s_ab[CHUNK * 136];   // out0/out0g bf16; later y0 f32 stage [16][132]
    __shared__ __align__(16) float s_u[CHUNK * 268];             // gate f32 / out1g bf16 / y1 f32 stage [16][388]
    __shared__ int s_nid[CHUNK];

    int t = threadIdx.x;
    int lane = t & 63, w = t >> 6, lr = lane & 15, lg = lane >> 4;
    int n = t >> 3, j = t & 7, f0 = j * 16;

    int nid = (n < cnt) ? wsI[WS_ORDER + start + n] : -1;
    if (j == 0) s_nid[n] = nid;

    const float* p = nf + (size_t)(nid >= 0 ? nid : 0) * 512;

    // ---- phase 1: polynomial paths (registers) ----
    float x0[16], dot[16], o0[16], c1[16];
    {
        #pragma unroll
        for (int v = 0; v < 4; ++v)
            *(float4*)&x0[4 * v] = *(const float4*)&p[f0 + 4 * v];
        #pragma unroll
        for (int h = 0; h < 2; ++h) {
            float q[24];
            #pragma unroll
            for (int v = 0; v < 6; ++v)
                *(float4*)&q[4 * v] = *(const float4*)&p[128 + f0 * 3 + 24 * h + 4 * v];
            #pragma unroll
            for (int i = 0; i < 8; ++i)
                dot[8 * h + i] = q[3 * i] * q[3 * i] + q[3 * i + 1] * q[3 * i + 1] + q[3 * i + 2] * q[3 * i + 2];
        }
        if (nid < 0) {
            #pragma unroll
            for (int i = 0; i < 16; ++i) { x0[i] = 0.f; dot[i] = 0.f; }
        }
        const float* W0 = w0 + s * 5 * F + f0;
        const float* W1 = w1 + s * 4 * F + f0;
        float wr[16];
        #define LOADW(base) { \
            *(float4*)&wr[0]  = *(const float4*)&(base)[0]; \
            *(float4*)&wr[4]  = *(const float4*)&(base)[4]; \
            *(float4*)&wr[8]  = *(const float4*)&(base)[8]; \
            *(float4*)&wr[12] = *(const float4*)&(base)[12]; }
        LOADW(W0);
        #pragma unroll
        for (int i = 0; i < 16; ++i) o0[i] = x0[i] * wr[i];
        LOADW((W0 + F));
        #pragma unroll
        for (int i = 0; i < 16; ++i) o0[i] += x0[i] * x0[i] * wr[i];
        LOADW((W0 + 2 * F));
        #pragma unroll
        for (int i = 0; i < 16; ++i) o0[i] += dot[i] * wr[i];
        LOADW((W0 + 3 * F));
        #pragma unroll
        for (int i = 0; i < 16; ++i) o0[i] += x0[i] * x0[i] * x0[i] * wr[i];
        LOADW((W0 + 4 * F));
        #pragma unroll
        for (int i = 0; i < 16; ++i) o0[i] += x0[i] * dot[i] * wr[i];
        LOADW(W1);
        #pragma unroll
        for (int i = 0; i < 16; ++i) c1[i] = wr[i];
        LOADW((W1 + F));
        #pragma unroll
        for (int i = 0; i < 16; ++i) c1[i] += x0[i] * wr[i];
        LOADW((W1 + 2 * F));
        #pragma unroll
        for (int i = 0; i < 16; ++i) c1[i] += x0[i] * x0[i] * wr[i];
        LOADW((W1 + 3 * F));
        #pragma unroll
        for (int i = 0; i < 16; ++i) c1[i] += dot[i] * wr[i];
        #undef LOADW
    }
    {
        uint4 pk0, pk1;
        pk0.x = pack2(o0[0], o0[1]);  pk0.y = pack2(o0[2], o0[3]);
        pk0.z = pack2(o0[4], o0[5]);  pk0.w = pack2(o0[6], o0[7]);
        pk1.x = pack2(o0[8], o0[9]);  pk1.y = pack2(o0[10], o0[11]);
        pk1.z = pack2(o0[12], o0[13]); pk1.w = pack2(o0[14], o0[15]);
        *(uint4*)&s_ab[n * 136 + f0] = pk0;
        *(uint4*)&s_ab[n * 136 + f0 + 8] = pk1;
    }

    // prefetch gate-kernel B-fragments (per wave: ot = 4w..4w+3)
    bf16x8 Bg[4][4];
    {
        const unsigned short* gkb = gkfrag + (size_t)((s * 16 + 4 * w) * 4) * 512 + lane * 8;
        #pragma unroll
        for (int oi = 0; oi < 4; ++oi)
            #pragma unroll
            for (int kk = 0; kk < 4; ++kk)
                Bg[oi][kk] = *(const bf16x8*)(gkb + (oi * 4 + kk) * 512);
    }
    __syncthreads();   // B1: s_ab ready

    // ---- phase 2: gate = out0 @ gk + gb, D[node][o] ----
    {
        int obase = w * 64;
        float gbv[4];
        #pragma unroll
        for (int oi = 0; oi < 4; ++oi) gbv[oi] = gb[s * NO + obase + oi * 16 + lr];
        #pragma unroll
        for (int nt = 0; nt < 2; ++nt) {
            bf16x8 A[4];
            #pragma unroll
            for (int kk = 0; kk < 4; ++kk)
                A[kk] = *(const bf16x8*)&s_ab[(nt * 16 + lr) * 136 + kk * 32 + lg * 8];
            #pragma unroll
            for (int oi = 0; oi < 4; ++oi) {
                f32x4 acc; acc[0] = gbv[oi]; acc[1] = gbv[oi]; acc[2] = gbv[oi]; acc[3] = gbv[oi];
                #pragma unroll
                for (int kk = 0; kk < 4; ++kk)
                    acc = __builtin_amdgcn_mfma_f32_16x16x32_bf16(A[kk], Bg[oi][kk], acc, 0, 0, 0);
                #pragma unroll
                for (int r = 0; r < 4; ++r)
                    s_u[(nt * 16 + lg * 4 + r) * 268 + obase + oi * 16 + lr] = acc[r];
            }
        }
    }
    __syncthreads();   // B2: gate ready

    // ---- phase 3a: read gate to regs ----
    float g0[16], g1[16];
    #pragma unroll
    for (int v = 0; v < 4; ++v)
        *(float4*)&g0[4 * v] = *(const float4*)&s_u[n * 268 + f0 + 4 * v];
    #pragma unroll
    for (int v = 0; v < 4; ++v)
        *(float4*)&g1[4 * v] = *(const float4*)&s_u[n * 268 + 128 + f0 + 4 * v];
    __syncthreads();   // B3: gate region reusable

    // ---- phase 3b: apply gate; emit out0g -> s_ab, out1g -> s_o1 (union) ----
    unsigned short* s_o1 = (unsigned short*)s_u;
    {
        #pragma unroll
        for (int i = 0; i < 16; ++i) { o0[i] *= g0[i]; c1[i] *= g1[i]; }
        uint4 pk0, pk1;
        pk0.x = pack2(o0[0], o0[1]);  pk0.y = pack2(o0[2], o0[3]);
        pk0.z = pack2(o0[4], o0[5]);  pk0.w = pack2(o0[6], o0[7]);
        pk1.x = pack2(o0[8], o0[9]);  pk1.y = pack2(o0[10], o0[11]);
        pk1.z = pack2(o0[12], o0[13]); pk1.w = pack2(o0[14], o0[15]);
        *(uint4*)&s_ab[n * 136 + f0] = pk0;
        *(uint4*)&s_ab[n * 136 + f0 + 8] = pk1;
    }
    // prefetch lin-weight B-fragments (per wave: gt = 2w, 2w+1)
    bf16x8 L0[2][4], L1[2][4];
    {
        const unsigned short* l0b = lw0f + (size_t)(w * 2 * 4) * 512 + lane * 8;
        const unsigned short* l1b = lw1f + (size_t)(w * 2 * 4) * 512 + lane * 8;
        #pragma unroll
        for (int gi = 0; gi < 2; ++gi)
            #pragma unroll
            for (int kk = 0; kk < 4; ++kk) {
                L0[gi][kk] = *(const bf16x8*)(l0b + (gi * 4 + kk) * 512);
                L1[gi][kk] = *(const bf16x8*)(l1b + (gi * 4 + kk) * 512);
            }
    }
    {
        #pragma unroll
        for (int h = 0; h < 2; ++h) {
            float q[24];
            #pragma unroll
            for (int v = 0; v < 6; ++v)
                *(float4*)&q[4 * v] = *(const float4*)&p[128 + f0 * 3 + 24 * h + 4 * v];
            if (nid < 0) {
                #pragma unroll
                for (int i = 0; i < 24; ++i) q[i] = 0.f;
            }
            #pragma unroll
            for (int d = 0; d < 3; ++d) {
                uint4 pk;
                pk.x = pack2(c1[8 * h + 0] * q[0 + d],  c1[8 * h + 1] * q[3 + d]);
                pk.y = pack2(c1[8 * h + 2] * q[6 + d],  c1[8 * h + 3] * q[9 + d]);
                pk.z = pack2(c1[8 * h + 4] * q[12 + d], c1[8 * h + 5] * q[15 + d]);
                pk.w = pack2(c1[8 * h + 6] * q[18 + d], c1[8 * h + 7] * q[21 + d]);
                *(uint4*)&s_o1[(d * CHUNK + n) * 136 + f0 + 8 * h] = pk;
            }
        }
    }
    __syncthreads();   // B4: out0g/out1g ready

    // ---- phase 4a: all MFMAs into registers ----
    f32x4 y0a[2][2];        // [nt][gi]
    f32x4 y1a[2][3][2];     // [nt][d][gi]
    #pragma unroll
    for (int nt = 0; nt < 2; ++nt) {
        bf16x8 A[4];
        #pragma unroll
        for (int kk = 0; kk < 4; ++kk)
            A[kk] = *(const bf16x8*)&s_ab[(nt * 16 + lr) * 136 + kk * 32 + lg * 8];
        #pragma unroll
        for (int gi = 0; gi < 2; ++gi) {
            f32x4 acc = {0.f, 0.f, 0.f, 0.f};
            #pragma unroll
            for (int kk = 0; kk < 4; ++kk)
                acc = __builtin_amdgcn_mfma_f32_16x16x32_bf16(A[kk], L0[gi][kk], acc, 0, 0, 0);
            y0a[nt][gi] = acc;
        }
        #pragma unroll
        for (int d = 0; d < 3; ++d) {
            bf16x8 Ad[4];
            #pragma unroll
            for (int kk = 0; kk < 4; ++kk)
                Ad[kk] = *(const bf16x8*)&s_o1[(d * CHUNK + nt * 16 + lr) * 136 + kk * 32 + lg * 8];
            #pragma unroll
            for (int gi = 0; gi < 2; ++gi) {
                f32x4 acc = {0.f, 0.f, 0.f, 0.f};
                #pragma unroll
                for (int kk = 0; kk < 4; ++kk)
                    acc = __builtin_amdgcn_mfma_f32_16x16x32_bf16(Ad[kk], L1[gi][kk], acc, 0, 0, 0);
                y1a[nt][d][gi] = acc;
            }
        }
    }
    __syncthreads();   // B5: all LDS reads of s_ab/s_u done

    // ---- phase 4b: stage + coalesced flush, one 16-node half at a time ----
    float* sy0 = (float*)s_ab;   // f32 [16][132]
    float* sy1 = s_u;            // f32 [16][388]
    #pragma unroll
    for (int nt = 0; nt < 2; ++nt) {
        #pragma unroll
        for (int gi = 0; gi < 2; ++gi)
            #pragma unroll
            for (int r = 0; r < 4; ++r)
                sy0[(lg * 4 + r) * 132 + w * 32 + gi * 16 + lr] = y0a[nt][gi][r];
        #pragma unroll
        for (int d = 0; d < 3; ++d)
            #pragma unroll
            for (int gi = 0; gi < 2; ++gi)
                #pragma unroll
                for (int r = 0; r < 4; ++r)
                    sy1[(lg * 4 + r) * 388 + (w * 32 + gi * 16 + lr) * 3 + d] = y1a[nt][d][gi][r];
        __syncthreads();   // staging visible
        {
            int node_l = t >> 4, inner = t & 15;
            int nid2 = s_nid[nt * 16 + node_l];
            if (nid2 >= 0) {
                float* orow = out + (size_t)nid2 * 512;
                #pragma unroll
                for (int it = 0; it < 2; ++it)
                    *(float4*)&orow[inner * 4 + it * 64] =
                        *(const float4*)&sy0[node_l * 132 + inner * 4 + it * 64];
                #pragma unroll
                for (int it = 0; it < 6; ++it)
                    *(float4*)&orow[128 + inner * 4 + it * 64] =
                        *(const float4*)&sy1[node_l * 388 + inner * 4 + it * 64];
            }
        }
        if (nt == 0) __syncthreads();   // staging reusable
    }
}

extern "C" void kernel_launch(void* const* d_in, const int* in_sizes, int n_in,
                              void* d_out, int out_size, void* d_ws, size_t ws_size,
                              hipStream_t stream) {
    const float* nf  = (const float*)d_in[0];
    const int*  spec = (const int*)d_in[1];
    const float* w0  = (const float*)d_in[2];
    const float* w1  = (const float*)d_in[3];
    const float* gk  = (const float*)d_in[4];
    const float* gb  = (const float*)d_in[5];
    const float* lw0 = (const float*)d_in[6];
    const float* lw1 = (const float*)d_in[7];
    float* out = (float*)d_out;

    int N = in_sizes[0] / (4 * F);
    int S = in_sizes[5] / NO;
    int* wsI = (int*)d_ws;
    unsigned* gkfrag = (unsigned*)((char*)d_ws + WS_GKFRAG);
    unsigned* lw0f   = (unsigned*)((char*)d_ws + WS_LW0FRAG);
    unsigned* lw1f   = (unsigned*)((char*)d_ws + WS_LW1FRAG);

    k_prep<<<S + 2, 256, 0, stream>>>(gk, lw0, lw1, wsI, gkfrag, lw0f, lw1f, S);
    k_hist<<<NBLK_HIST, 256, 0, stream>>>(spec, N, wsI);
    k_plan<<<1, 64, 0, stream>>>(wsI, S);
    k_scatter<<<NBLK_HIST, 256, 0, stream>>>(spec, N, wsI);

    int maxc = (N + CHUNK - 1) / CHUNK + S;
    k_main<<<maxc, THREADS, 0, stream>>>(nf, w0, w1,
                                         (const unsigned short*)gkfrag, gb,
                                         (const unsigned short*)lw0f,
                                         (const unsigned short*)lw1f,
                                         wsI, out);
}